// Round 7
// baseline (173.830 us; speedup 1.0000x reference)
//
#include <hip/hip_runtime.h>

#define NNODES 50000
#define NEDGES 600000
#define NGRAPHS 64
#define SCAN_BLOCKS ((NNODES + 255) / 256)   // 196

typedef __attribute__((ext_vector_type(8))) short short8;
typedef __attribute__((ext_vector_type(4))) float f32x4;

__device__ inline short f2bf(float f) {
    unsigned u = __float_as_uint(f);
    u = (u + 0x7fffu + ((u >> 16) & 1u)) >> 16;   // RNE
    return (short)u;
}
__device__ inline float bf2f(unsigned short s) {
    return __uint_as_float(((unsigned)s) << 16);
}
__device__ inline float bf_lo(unsigned w) { return __uint_as_float(w << 16); }
__device__ inline float bf_hi(unsigned w) { return __uint_as_float(w & 0xffff0000u); }
__device__ inline void addbf8(const uint4 m, float* a) {
    a[0] += bf_lo(m.x); a[1] += bf_hi(m.x);
    a[2] += bf_lo(m.y); a[3] += bf_hi(m.y);
    a[4] += bf_lo(m.z); a[5] += bf_hi(m.z);
    a[6] += bf_lo(m.w); a[7] += bf_hi(m.w);
}

// ---------- init: W frag tables, zero rp/part/out ----------
__device__ inline uint4 make_frag(const float* __restrict__ W, int M, int idx) {
    int lane = idx & 63, ks = (idx >> 6) & 3, cf = idx >> 8;
    int c = cf * 16 + (lane & 15);
    int k0 = ks * 32 + (lane >> 4) * 8;
    unsigned t[8];
    #pragma unroll
    for (int j = 0; j < 8; ++j)
        t[j] = (unsigned short)f2bf(W[(k0 + j) * M + c]);
    uint4 o;
    o.x = t[0] | (t[1] << 16);
    o.y = t[2] | (t[3] << 16);
    o.z = t[4] | (t[5] << 16);
    o.w = t[6] | (t[7] << 16);
    return o;
}

__global__ __launch_bounds__(256) void k_init0(const float* __restrict__ W1,
                                               const float* __restrict__ W2,
                                               unsigned short* __restrict__ Wf1,
                                               unsigned short* __restrict__ Wf2,
                                               int* __restrict__ rp,
                                               unsigned long long* __restrict__ part,
                                               float* __restrict__ dout) {
    int idx = blockIdx.x * 256 + threadIdx.x;     // 16 blocks = 4096 threads
    for (int i = idx; i < NNODES + 1; i += 4096) rp[i] = 0;
    if (idx < SCAN_BLOCKS) part[idx] = 0ULL;
    if (idx < NGRAPHS * 64) dout[idx] = 0.f;
    if (idx < 2048) {
        ((uint4*)Wf1)[idx] = make_frag(W1, 128, idx);
    } else if (idx < 3072) {
        ((uint4*)Wf2)[idx - 2048] = make_frag(W2, 64, idx - 2048);
    }
}

// ---------- mega1: blocks 0..195 = GEMM1 (Y = bf16(x@W1), no dinv); 196..781 = degree count ----------
#define GEMM_BLKS 196
__global__ __launch_bounds__(256) void k_mega1(const float* __restrict__ X,
                                               const unsigned short* __restrict__ Wf,
                                               unsigned short* __restrict__ Y,
                                               const int* __restrict__ ei,
                                               int* __restrict__ rp) {
    const int tid = threadIdx.x;
    if (blockIdx.x >= GEMM_BLKS) {
        int idx = (blockIdx.x - GEMM_BLKS) * 256 + tid;     // 4 edges/thread
        if (idx * 4 < NEDGES) {
            int4 d = ((const int4*)(ei + NEDGES))[idx];
            atomicAdd(&rp[1 + d.x], 1);
            atomicAdd(&rp[1 + d.y], 1);
            atomicAdd(&rp[1 + d.z], 1);
            atomicAdd(&rp[1 + d.w], 1);
        }
        return;
    }
    constexpr int CF = 8;
    constexpr int SLOTS = CF * 4 * 64;   // 2048
    __shared__ uint4 Bl[SLOTS];
    for (int i = tid; i < SLOTS; i += 256) Bl[i] = ((const uint4*)Wf)[i];
    __syncthreads();

    const short8* Bs8 = (const short8*)Bl;
    const int lane = tid & 63;
    const int wave = tid >> 6;
    const int qr = lane >> 4;
    const int cl = lane & 15;
    const int wid = blockIdx.x * 4 + wave;
    const int ngroups = (NNODES + 63) / 64;   // 782
    if (wid >= ngroups) return;

    const int base = wid * 64;
    short8 a[4][4];
    #pragma unroll
    for (int r = 0; r < 4; ++r) {
        int arow = base + r * 16 + cl;
        bool ok = arow < NNODES;
        #pragma unroll
        for (int ks = 0; ks < 4; ++ks) {
            short8 v = (short8)0;
            if (ok) {
                const float* xp = X + (long)arow * 128 + ks * 32 + qr * 8;
                float4 x0 = *reinterpret_cast<const float4*>(xp);
                float4 x1 = *reinterpret_cast<const float4*>(xp + 4);
                v[0] = f2bf(x0.x); v[1] = f2bf(x0.y); v[2] = f2bf(x0.z); v[3] = f2bf(x0.w);
                v[4] = f2bf(x1.x); v[5] = f2bf(x1.y); v[6] = f2bf(x1.z); v[7] = f2bf(x1.w);
            }
            a[r][ks] = v;
        }
    }
    f32x4 acc[4][CF];
    #pragma unroll
    for (int r = 0; r < 4; ++r)
        #pragma unroll
        for (int cf = 0; cf < CF; ++cf)
            acc[r][cf] = (f32x4){0.f, 0.f, 0.f, 0.f};
    #pragma unroll
    for (int cf = 0; cf < CF; ++cf)
        #pragma unroll
        for (int ks = 0; ks < 4; ++ks) {
            short8 b = Bs8[(cf * 4 + ks) * 64 + lane];
            #pragma unroll
            for (int r = 0; r < 4; ++r)
                acc[r][cf] = __builtin_amdgcn_mfma_f32_16x16x32_bf16(a[r][ks], b, acc[r][cf], 0, 0, 0);
        }
    #pragma unroll
    for (int r = 0; r < 4; ++r) {
        int row0 = base + r * 16 + qr * 4;
        #pragma unroll
        for (int i = 0; i < 4; ++i) {
            int row = row0 + i;
            if (row < NNODES) {
                #pragma unroll
                for (int cf = 0; cf < CF; ++cf)
                    Y[(long)row * 128 + cf * 16 + cl] = (unsigned short)f2bf(acc[r][cf][i]);
            }
        }
    }
}

// ---------- decoupled-lookback scan; emits rowptr(incl), cursor(excl), dinv ----------
__global__ __launch_bounds__(256) void k_scan_lb(int* __restrict__ rp,
                                                 unsigned long long* __restrict__ part,
                                                 int* __restrict__ cur,
                                                 float* __restrict__ dinv) {
    __shared__ int s[256];
    __shared__ int base_sh;
    int t = threadIdx.x;
    int bid = blockIdx.x;
    int idx = bid * 256 + t;
    int c = (idx < NNODES) ? rp[1 + idx] : 0;
    s[t] = c;
    __syncthreads();
    for (int off = 1; off < 256; off <<= 1) {
        int u = (t >= off) ? s[t - off] : 0;
        __syncthreads();
        s[t] += u;
        __syncthreads();
    }
    if (t == 0) {
        int agg = s[255];
        atomicExch(&part[bid], (1ULL << 32) | (unsigned)agg);
        long long base = 0;
        for (int j = bid - 1; j >= 0; --j) {
            unsigned long long w;
            do { w = atomicAdd(&part[j], 0ULL); } while ((w >> 32) == 0ULL);
            base += (int)(w & 0xffffffffu);
            if ((w >> 32) == 2ULL) break;
        }
        atomicExch(&part[bid], (2ULL << 32) | (unsigned)(base + agg));
        base_sh = (int)base;
    }
    __syncthreads();
    int incl = s[t] + base_sh;
    if (idx < NNODES) {
        rp[1 + idx] = incl;
        cur[idx] = incl - c;
        dinv[idx] = rsqrtf((float)c + 1.0f);
    }
}

__global__ __launch_bounds__(256) void k_scatter(const int* __restrict__ ei,
                                                 int* __restrict__ cur,
                                                 int* __restrict__ csr_src) {
    int idx = blockIdx.x * 256 + threadIdx.x;       // 4 edges/thread
    if (idx * 4 >= NEDGES) return;
    int4 sv = ((const int4*)ei)[idx];
    int4 dv = ((const int4*)(ei + NEDGES))[idx];
    int p0 = atomicAdd(&cur[dv.x], 1); csr_src[p0] = sv.x;
    int p1 = atomicAdd(&cur[dv.y], 1); csr_src[p1] = sv.y;
    int p2 = atomicAdd(&cur[dv.z], 1); csr_src[p2] = sv.z;
    int p3 = atomicAdd(&cur[dv.w], 1); csr_src[p3] = sv.w;
}

// ---------- fused: gather layer-1 (per-edge dinv, relu+bias) -> LDS -> @W2 -> Hs2 bf16 ----------
// Phase A: one node per wave pass, 64 lanes x dword (2 ch each) -> no divergence,
// wave-uniform csr/dinv loads (scalarized). LDS rows XOR-swizzled.
__global__ __launch_bounds__(256) void k_gather_gemm(const int* __restrict__ rp,
                                                     const int* __restrict__ csr_src,
                                                     const float* __restrict__ dinv,
                                                     const unsigned short* __restrict__ Hs,
                                                     const float* __restrict__ b1,
                                                     const unsigned short* __restrict__ Wf2,
                                                     unsigned short* __restrict__ Y) {
    __shared__ uint4 Bl[1024];                 // W2 frags, 16 KB
    __shared__ unsigned h1[64 * 64];           // 16 KB = [64 rows][128 bf16], swizzled
    const int tid = threadIdx.x;
    const int lane = tid & 63;
    const int wave = tid >> 6;
    for (int i = tid; i < 1024; i += 256) Bl[i] = ((const uint4*)Wf2)[i];

    const int base = blockIdx.x * 64;
    const unsigned* Hr = (const unsigned*)Hs;  // row = 64 dwords (128 bf16)
    float2 bb = ((const float2*)b1)[lane];     // ch 2*lane, 2*lane+1

    for (int p = 0; p < 16; ++p) {
        int vloc = wave * 16 + p;
        int v = base + vloc;
        unsigned o = 0u;
        if (v < NNODES) {
            float dd = dinv[v];
            unsigned sw = Hr[(long)v * 64 + lane];
            float a0 = bf_lo(sw) * dd;
            float a1 = bf_hi(sw) * dd;
            int lo = rp[v], hi = rp[v + 1];
            int i = lo;
            for (; i + 4 <= hi; i += 4) {
                int s0 = csr_src[i], s1 = csr_src[i + 1];
                int s2 = csr_src[i + 2], s3 = csr_src[i + 3];
                float n0 = dinv[s0], n1 = dinv[s1], n2 = dinv[s2], n3 = dinv[s3];
                unsigned w0 = Hr[(long)s0 * 64 + lane];
                unsigned w1 = Hr[(long)s1 * 64 + lane];
                unsigned w2 = Hr[(long)s2 * 64 + lane];
                unsigned w3 = Hr[(long)s3 * 64 + lane];
                a0 = fmaf(bf_lo(w0), n0, a0); a1 = fmaf(bf_hi(w0), n0, a1);
                a0 = fmaf(bf_lo(w1), n1, a0); a1 = fmaf(bf_hi(w1), n1, a1);
                a0 = fmaf(bf_lo(w2), n2, a0); a1 = fmaf(bf_hi(w2), n2, a1);
                a0 = fmaf(bf_lo(w3), n3, a0); a1 = fmaf(bf_hi(w3), n3, a1);
            }
            for (; i < hi; ++i) {
                int s = csr_src[i];
                float n = dinv[s];
                unsigned w = Hr[(long)s * 64 + lane];
                a0 = fmaf(bf_lo(w), n, a0);
                a1 = fmaf(bf_hi(w), n, a1);
            }
            float y0 = fmaxf(fmaf(a0, dd, bb.x), 0.f);
            float y1 = fmaxf(fmaf(a1, dd, bb.y), 0.f);
            o = (unsigned)(unsigned short)f2bf(y0) | ((unsigned)(unsigned short)f2bf(y1) << 16);
        }
        *reinterpret_cast<unsigned*>((char*)h1 +
            ((vloc * 256 + lane * 4) ^ ((vloc & 7) << 4))) = o;
    }
    __syncthreads();

    // Phase B: rows wave*16..+15 ; A-frag: row=wave*16+cl, ch=ks*32+qr*8
    const int qr = lane >> 4;
    const int cl = lane & 15;
    const int arow = wave * 16 + cl;
    short8 afr[4];
    #pragma unroll
    for (int ks = 0; ks < 4; ++ks) {
        int byte = (arow * 256 + (ks * 32 + qr * 8) * 2) ^ ((arow & 7) << 4);
        afr[ks] = *reinterpret_cast<const short8*>((const char*)h1 + byte);
    }
    const short8* Bs8 = (const short8*)Bl;
    f32x4 acc[4];
    #pragma unroll
    for (int cf = 0; cf < 4; ++cf) acc[cf] = (f32x4){0.f, 0.f, 0.f, 0.f};
    #pragma unroll
    for (int cf = 0; cf < 4; ++cf)
        #pragma unroll
        for (int ks = 0; ks < 4; ++ks)
            acc[cf] = __builtin_amdgcn_mfma_f32_16x16x32_bf16(afr[ks], Bs8[(cf * 4 + ks) * 64 + lane], acc[cf], 0, 0, 0);
    #pragma unroll
    for (int i = 0; i < 4; ++i) {
        int row = base + wave * 16 + qr * 4 + i;
        if (row < NNODES) {
            float dv = dinv[row];
            #pragma unroll
            for (int cf = 0; cf < 4; ++cf)
                Y[(long)row * 64 + cf * 16 + cl] = (unsigned short)f2bf(acc[cf][i] * dv);
        }
    }
}

// ---------- CSR gather layer 2: out[v] = dinv[v]*(Hs[v]+sum Hs[s]) + b2 (bf16) ----------
__global__ __launch_bounds__(256) void k_gather2(const int* __restrict__ rp,
                                                 const int* __restrict__ csr_src,
                                                 const float* __restrict__ dinv,
                                                 const unsigned short* __restrict__ Hs,
                                                 const float* __restrict__ bias,
                                                 unsigned short* __restrict__ out) {
    int lane = threadIdx.x & 7;          // 8 lanes/node, 8 ch each
    int grp = threadIdx.x >> 3;
    int v = blockIdx.x * 32 + grp;
    if (v >= NNODES) return;
    int c8 = lane * 8;
    float dd = dinv[v];
    float a[8] = {0, 0, 0, 0, 0, 0, 0, 0};
    const uint4* Hp = (const uint4*)Hs;
    addbf8(Hp[((long)v * 64 + c8) >> 3], a);
    int lo = rp[v], hi = rp[v + 1];
    int i = lo;
    for (; i + 8 <= hi; i += 8) {
        int ss[8];
        #pragma unroll
        for (int j = 0; j < 8; ++j) ss[j] = csr_src[i + j];
        uint4 mm[8];
        #pragma unroll
        for (int j = 0; j < 8; ++j) mm[j] = Hp[((long)ss[j] * 64 + c8) >> 3];
        #pragma unroll
        for (int j = 0; j < 8; ++j) addbf8(mm[j], a);
    }
    for (; i + 4 <= hi; i += 4) {
        int ss[4];
        #pragma unroll
        for (int j = 0; j < 4; ++j) ss[j] = csr_src[i + j];
        uint4 mm[4];
        #pragma unroll
        for (int j = 0; j < 4; ++j) mm[j] = Hp[((long)ss[j] * 64 + c8) >> 3];
        #pragma unroll
        for (int j = 0; j < 4; ++j) addbf8(mm[j], a);
    }
    for (; i < hi; ++i)
        addbf8(Hp[((long)csr_src[i] * 64 + c8) >> 3], a);
    unsigned t[8];
    #pragma unroll
    for (int j = 0; j < 8; ++j)
        t[j] = (unsigned short)f2bf(fmaf(a[j], dd, bias[c8 + j]));
    uint4 o;
    o.x = t[0] | (t[1] << 16);
    o.y = t[2] | (t[3] << 16);
    o.z = t[4] | (t[5] << 16);
    o.w = t[6] | (t[7] << 16);
    ((uint4*)out)[((long)v * 64 + c8) >> 3] = o;
}

// ---------- pool ----------
__device__ inline int lower_bound_i(const int* a, int n, int key) {
    int lo = 0, hi = n;
    while (lo < hi) {
        int mid = (lo + hi) >> 1;
        if (a[mid] < key) lo = mid + 1; else hi = mid;
    }
    return lo;
}

__global__ __launch_bounds__(256) void k_pool(const unsigned short* __restrict__ h2,
                                              const int* __restrict__ batch,
                                              float* __restrict__ out) {
    int g = blockIdx.x >> 4;
    int slice = blockIdx.x & 15;
    int lo = lower_bound_i(batch, NNODES, g);
    int hi = lower_bound_i(batch, NNODES, g + 1);
    int ch = threadIdx.x & 63;
    int part = threadIdx.x >> 6;
    float acc = 0.f;
    for (int v = lo + slice * 4 + part; v < hi; v += 64)
        acc += bf2f(h2[(long)v * 64 + ch]);
    __shared__ float red[256];
    red[threadIdx.x] = acc;
    __syncthreads();
    if (part == 0) {
        float s = red[ch] + red[64 + ch] + red[128 + ch] + red[192 + ch];
        atomicAdd(&out[g * 64 + ch], s);
    }
}

// ---------- launch ----------
extern "C" void kernel_launch(void* const* d_in, const int* in_sizes, int n_in,
                              void* d_out, int out_size, void* d_ws, size_t ws_size,
                              hipStream_t stream) {
    const float* x   = (const float*)d_in[0];
    const int* ei    = (const int*)d_in[1];
    const int* batch = (const int*)d_in[2];
    const float* W1  = (const float*)d_in[3];
    const float* b1  = (const float*)d_in[4];
    const float* W2  = (const float*)d_in[5];
    const float* b2  = (const float*)d_in[6];
    float* out = (float*)d_out;

    char* ws = (char*)d_ws;
    float* dinv   = (float*)ws;                                 // 200 KB
    int*   rp     = (int*)(ws + (256 << 10));                   // 50001 ints
    unsigned long long* part = (unsigned long long*)(ws + (512 << 10)); // 1.6 KB
    int*   cursor = (int*)(ws + (576 << 10));                   // 200 KB
    int*   csr    = (int*)(ws + (1u << 20));                    // 2.4 MB
    unsigned short* Wf1 = (unsigned short*)(ws + (3600u << 10));            // 32 KB
    unsigned short* Wf2 = (unsigned short*)(ws + (3600u << 10) + (32 << 10)); // 16 KB
    unsigned short* bufA = (unsigned short*)(ws + (4u << 20));              // 12.8 MB
    unsigned short* bufB = (unsigned short*)(ws + (4u << 20) + (size_t)NNODES * 128 * 2); // 6.4 MB

    // init (zero rp/part/out, build W frags)
    k_init0<<<16, 256, 0, stream>>>(W1, W2, Wf1, Wf2, rp, part, out);

    // mega1: GEMM1 (blocks 0..195) || degree count (blocks 196..781)
    k_mega1<<<GEMM_BLKS + (NEDGES / 4 + 255) / 256, 256, 0, stream>>>(x, Wf1, bufA, ei, rp);

    // scan -> rowptr/cursor/dinv ; scatter -> csr
    k_scan_lb<<<SCAN_BLOCKS, 256, 0, stream>>>(rp, part, cursor, dinv);
    k_scatter<<<(NEDGES / 4 + 255) / 256, 256, 0, stream>>>(ei, cursor, csr);

    // fused gather1(+bias+relu, per-edge dinv) -> @W2 -> Hs2
    k_gather_gemm<<<(NNODES + 63) / 64, 256, 0, stream>>>(rp, csr, dinv, bufA, b1, Wf2, bufB);

    // gather2 (+bias) -> bufA region
    k_gather2<<<(NNODES + 31) / 32, 256, 0, stream>>>(rp, csr, dinv, bufB, b2, bufA);

    // pool
    k_pool<<<NGRAPHS * 16, 256, 0, stream>>>(bufA, batch, out);
}

// Round 8
// 138.787 us; speedup vs baseline: 1.2525x; 1.2525x over previous
//
#include <hip/hip_runtime.h>

#define NNODES 50000
#define NEDGES 600000
#define NGRAPHS 64
#define SCAN_BLOCKS ((NNODES + 255) / 256)   // 196

typedef __attribute__((ext_vector_type(8))) short short8;
typedef __attribute__((ext_vector_type(4))) float f32x4;

__device__ inline short f2bf(float f) {
    unsigned u = __float_as_uint(f);
    u = (u + 0x7fffu + ((u >> 16) & 1u)) >> 16;   // RNE
    return (short)u;
}
__device__ inline float bf2f(unsigned short s) {
    return __uint_as_float(((unsigned)s) << 16);
}
__device__ inline float bf_lo(unsigned w) { return __uint_as_float(w << 16); }
__device__ inline float bf_hi(unsigned w) { return __uint_as_float(w & 0xffff0000u); }
__device__ inline void fmabf8(const uint4 m, float n, float* a) {
    a[0] = fmaf(bf_lo(m.x), n, a[0]); a[1] = fmaf(bf_hi(m.x), n, a[1]);
    a[2] = fmaf(bf_lo(m.y), n, a[2]); a[3] = fmaf(bf_hi(m.y), n, a[3]);
    a[4] = fmaf(bf_lo(m.z), n, a[4]); a[5] = fmaf(bf_hi(m.z), n, a[5]);
    a[6] = fmaf(bf_lo(m.w), n, a[6]); a[7] = fmaf(bf_hi(m.w), n, a[7]);
}
__device__ inline void addbf8(const uint4 m, float* a) {
    a[0] += bf_lo(m.x); a[1] += bf_hi(m.x);
    a[2] += bf_lo(m.y); a[3] += bf_hi(m.y);
    a[4] += bf_lo(m.z); a[5] += bf_hi(m.z);
    a[6] += bf_lo(m.w); a[7] += bf_hi(m.w);
}

// ---------- init: W frag tables, zero rp, zero out ----------
// frag slot idx = (cf*4+ks)*64+lane ; elem j: W[ks*32+(lane>>4)*8+j][cf*16+(lane&15)]
__device__ inline uint4 make_frag(const float* __restrict__ W, int M, int idx) {
    int lane = idx & 63, ks = (idx >> 6) & 3, cf = idx >> 8;
    int c = cf * 16 + (lane & 15);
    int k0 = ks * 32 + (lane >> 4) * 8;
    unsigned t[8];
    #pragma unroll
    for (int j = 0; j < 8; ++j)
        t[j] = (unsigned short)f2bf(W[(k0 + j) * M + c]);
    uint4 o;
    o.x = t[0] | (t[1] << 16);
    o.y = t[2] | (t[3] << 16);
    o.z = t[4] | (t[5] << 16);
    o.w = t[6] | (t[7] << 16);
    return o;
}

__global__ __launch_bounds__(256) void k_init0(const float* __restrict__ W1,
                                               const float* __restrict__ W2,
                                               unsigned short* __restrict__ Wf1,
                                               unsigned short* __restrict__ Wf2,
                                               int* __restrict__ rp,
                                               float* __restrict__ dout) {
    int idx = blockIdx.x * 256 + threadIdx.x;     // 16 blocks = 4096 threads
    for (int i = idx; i < NNODES + 1; i += 4096) rp[i] = 0;
    if (idx < NGRAPHS * 64) dout[idx] = 0.f;
    if (idx < 2048) {
        ((uint4*)Wf1)[idx] = make_frag(W1, 128, idx);
    } else if (idx < 3072) {
        ((uint4*)Wf2)[idx - 2048] = make_frag(W2, 64, idx - 2048);
    }
}

// ---------- mega1: blocks 0..195 = GEMM1 (Y = bf16(x@W1), NO dinv); rest = degree count ----------
#define GEMM_BLKS 196
__global__ __launch_bounds__(256) void k_mega1(const float* __restrict__ X,
                                               const unsigned short* __restrict__ Wf,
                                               unsigned short* __restrict__ Y,
                                               const int* __restrict__ ei,
                                               int* __restrict__ rp) {
    const int tid = threadIdx.x;
    if (blockIdx.x >= GEMM_BLKS) {
        int idx = (blockIdx.x - GEMM_BLKS) * 256 + tid;     // 4 edges/thread
        if (idx * 4 < NEDGES) {
            int4 d = ((const int4*)(ei + NEDGES))[idx];
            atomicAdd(&rp[1 + d.x], 1);
            atomicAdd(&rp[1 + d.y], 1);
            atomicAdd(&rp[1 + d.z], 1);
            atomicAdd(&rp[1 + d.w], 1);
        }
        return;
    }
    constexpr int CF = 8;
    constexpr int SLOTS = CF * 4 * 64;   // 2048
    __shared__ uint4 Bl[SLOTS];
    for (int i = tid; i < SLOTS; i += 256) Bl[i] = ((const uint4*)Wf)[i];
    __syncthreads();

    const short8* Bs8 = (const short8*)Bl;
    const int lane = tid & 63;
    const int wave = tid >> 6;
    const int qr = lane >> 4;
    const int cl = lane & 15;
    const int wid = blockIdx.x * 4 + wave;
    const int ngroups = (NNODES + 63) / 64;   // 782
    if (wid >= ngroups) return;

    const int base = wid * 64;
    short8 a[4][4];
    #pragma unroll
    for (int r = 0; r < 4; ++r) {
        int arow = base + r * 16 + cl;
        bool ok = arow < NNODES;
        #pragma unroll
        for (int ks = 0; ks < 4; ++ks) {
            short8 v = (short8)0;
            if (ok) {
                const float* xp = X + (long)arow * 128 + ks * 32 + qr * 8;
                float4 x0 = *reinterpret_cast<const float4*>(xp);
                float4 x1 = *reinterpret_cast<const float4*>(xp + 4);
                v[0] = f2bf(x0.x); v[1] = f2bf(x0.y); v[2] = f2bf(x0.z); v[3] = f2bf(x0.w);
                v[4] = f2bf(x1.x); v[5] = f2bf(x1.y); v[6] = f2bf(x1.z); v[7] = f2bf(x1.w);
            }
            a[r][ks] = v;
        }
    }
    f32x4 acc[4][CF];
    #pragma unroll
    for (int r = 0; r < 4; ++r)
        #pragma unroll
        for (int cf = 0; cf < CF; ++cf)
            acc[r][cf] = (f32x4){0.f, 0.f, 0.f, 0.f};
    #pragma unroll
    for (int cf = 0; cf < CF; ++cf)
        #pragma unroll
        for (int ks = 0; ks < 4; ++ks) {
            short8 b = Bs8[(cf * 4 + ks) * 64 + lane];
            #pragma unroll
            for (int r = 0; r < 4; ++r)
                acc[r][cf] = __builtin_amdgcn_mfma_f32_16x16x32_bf16(a[r][ks], b, acc[r][cf], 0, 0, 0);
        }
    #pragma unroll
    for (int r = 0; r < 4; ++r) {
        int row0 = base + r * 16 + qr * 4;
        #pragma unroll
        for (int i = 0; i < 4; ++i) {
            int row = row0 + i;
            if (row < NNODES) {
                #pragma unroll
                for (int cf = 0; cf < CF; ++cf)
                    Y[(long)row * 128 + cf * 16 + cl] = (unsigned short)f2bf(acc[r][cf][i]);
            }
        }
    }
}

// ---------- scan cascade (known-good from R4) ----------
__global__ __launch_bounds__(256) void k_bsum(const int* __restrict__ rp,
                                              int* __restrict__ bsum) {
    __shared__ int red[256];
    int idx = blockIdx.x * 256 + threadIdx.x;
    red[threadIdx.x] = (idx < NNODES) ? rp[1 + idx] : 0;
    __syncthreads();
    for (int off = 128; off > 0; off >>= 1) {
        if (threadIdx.x < off) red[threadIdx.x] += red[threadIdx.x + off];
        __syncthreads();
    }
    if (threadIdx.x == 0) bsum[blockIdx.x] = red[0];
}

__global__ __launch_bounds__(256) void k_scan_bsum(int* __restrict__ bsum) {
    __shared__ int s[256];
    int t = threadIdx.x;
    s[t] = (t < SCAN_BLOCKS) ? bsum[t] : 0;
    __syncthreads();
    for (int off = 1; off < 256; off <<= 1) {
        int u = (t >= off) ? s[t - off] : 0;
        __syncthreads();
        s[t] += u;
        __syncthreads();
    }
    if (t < SCAN_BLOCKS) bsum[t] = s[t];
}

__global__ __launch_bounds__(256) void k_scan_final(int* __restrict__ rp,
                                                    const int* __restrict__ bsum,
                                                    int* __restrict__ cur,
                                                    float* __restrict__ dinv) {
    __shared__ int s[256];
    int t = threadIdx.x;
    int idx = blockIdx.x * 256 + t;
    int c = (idx < NNODES) ? rp[1 + idx] : 0;
    s[t] = c;
    __syncthreads();
    for (int off = 1; off < 256; off <<= 1) {
        int u = (t >= off) ? s[t - off] : 0;
        __syncthreads();
        s[t] += u;
        __syncthreads();
    }
    int incl = s[t] + (blockIdx.x ? bsum[blockIdx.x - 1] : 0);
    if (idx < NNODES) {
        rp[1 + idx] = incl;
        cur[idx] = incl - c;
        dinv[idx] = rsqrtf((float)c + 1.0f);
    }
}

__global__ __launch_bounds__(256) void k_scatter(const int* __restrict__ ei,
                                                 int* __restrict__ cur,
                                                 int* __restrict__ csr_src) {
    int idx = blockIdx.x * 256 + threadIdx.x;       // 4 edges/thread
    if (idx * 4 >= NEDGES) return;
    int4 sv = ((const int4*)ei)[idx];
    int4 dv = ((const int4*)(ei + NEDGES))[idx];
    int p0 = atomicAdd(&cur[dv.x], 1); csr_src[p0] = sv.x;
    int p1 = atomicAdd(&cur[dv.y], 1); csr_src[p1] = sv.y;
    int p2 = atomicAdd(&cur[dv.z], 1); csr_src[p2] = sv.z;
    int p3 = atomicAdd(&cur[dv.w], 1); csr_src[p3] = sv.w;
}

// ---------- fused: gather layer-1 (per-edge dinv[src], relu+bias) -> LDS -> @W2 ----------
// Phase A (R4-proven MLP structure): 4 nodes/wave, 16 lanes/node, uint4/lane,
// unroll-4 edge loop; per-edge dinv[s] broadcast folded via fmaf.
__global__ __launch_bounds__(256) void k_gather_gemm(const int* __restrict__ rp,
                                                     const int* __restrict__ csr_src,
                                                     const float* __restrict__ dinv,
                                                     const unsigned short* __restrict__ Hs,
                                                     const float* __restrict__ b1,
                                                     const unsigned short* __restrict__ Wf2,
                                                     unsigned short* __restrict__ Y) {
    __shared__ uint4 Bl[1024];                 // W2 frags, 16 KB
    __shared__ unsigned short h1[64 * 128];    // 16 KB, XOR-swizzled rows
    const int tid = threadIdx.x;
    const int lane = tid & 63;
    const int wave = tid >> 6;
    for (int i = tid; i < 1024; i += 256) Bl[i] = ((const uint4*)Wf2)[i];

    const int grp = lane >> 4;
    const int ln = lane & 15;
    const int c8 = ln * 8;
    const int base = blockIdx.x * 64;
    const uint4* Hp = (const uint4*)Hs;
    float4 bv0 = *reinterpret_cast<const float4*>(b1 + c8);
    float4 bv1 = *reinterpret_cast<const float4*>(b1 + c8 + 4);
    float bb[8] = {bv0.x, bv0.y, bv0.z, bv0.w, bv1.x, bv1.y, bv1.z, bv1.w};

    #pragma unroll
    for (int p = 0; p < 4; ++p) {
        int vloc = wave * 16 + p * 4 + grp;
        int v = base + vloc;
        uint4 o = {0u, 0u, 0u, 0u};
        if (v < NNODES) {
            float a[8] = {0, 0, 0, 0, 0, 0, 0, 0};
            float dd = dinv[v];
            fmabf8(Hp[((long)v * 128 + c8) >> 3], dd, a);   // self * dinv[v]
            int lo = rp[v], hi = rp[v + 1];
            int i = lo;
            for (; i + 4 <= hi; i += 4) {
                int s0 = csr_src[i], s1 = csr_src[i + 1];
                int s2 = csr_src[i + 2], s3 = csr_src[i + 3];
                float n0 = dinv[s0], n1 = dinv[s1], n2 = dinv[s2], n3 = dinv[s3];
                uint4 m0 = Hp[((long)s0 * 128 + c8) >> 3];
                uint4 m1 = Hp[((long)s1 * 128 + c8) >> 3];
                uint4 m2 = Hp[((long)s2 * 128 + c8) >> 3];
                uint4 m3 = Hp[((long)s3 * 128 + c8) >> 3];
                fmabf8(m0, n0, a); fmabf8(m1, n1, a);
                fmabf8(m2, n2, a); fmabf8(m3, n3, a);
            }
            for (; i < hi; ++i) {
                int s = csr_src[i];
                fmabf8(Hp[((long)s * 128 + c8) >> 3], dinv[s], a);
            }
            unsigned t[8];
            #pragma unroll
            for (int j = 0; j < 8; ++j) {
                float y = fmaxf(fmaf(a[j], dd, bb[j]), 0.f);
                t[j] = (unsigned short)f2bf(y);
            }
            o.x = t[0] | (t[1] << 16);
            o.y = t[2] | (t[3] << 16);
            o.z = t[4] | (t[5] << 16);
            o.w = t[6] | (t[7] << 16);
        }
        int byte = (vloc * 256 + c8 * 2) ^ ((vloc & 7) << 4);
        *reinterpret_cast<uint4*>((char*)h1 + byte) = o;
    }
    __syncthreads();

    // Phase B: rows wave*16..+15 ; A-frag: row=wave*16+cl, ch=ks*32+qr*8
    const int qr = lane >> 4;
    const int cl = lane & 15;
    const int arow = wave * 16 + cl;
    short8 afr[4];
    #pragma unroll
    for (int ks = 0; ks < 4; ++ks) {
        int byte = (arow * 256 + (ks * 32 + qr * 8) * 2) ^ ((arow & 7) << 4);
        afr[ks] = *reinterpret_cast<const short8*>((const char*)h1 + byte);
    }
    const short8* Bs8 = (const short8*)Bl;
    f32x4 acc[4];
    #pragma unroll
    for (int cf = 0; cf < 4; ++cf) acc[cf] = (f32x4){0.f, 0.f, 0.f, 0.f};
    #pragma unroll
    for (int cf = 0; cf < 4; ++cf)
        #pragma unroll
        for (int ks = 0; ks < 4; ++ks)
            acc[cf] = __builtin_amdgcn_mfma_f32_16x16x32_bf16(afr[ks], Bs8[(cf * 4 + ks) * 64 + lane], acc[cf], 0, 0, 0);
    #pragma unroll
    for (int i = 0; i < 4; ++i) {
        int row = base + wave * 16 + qr * 4 + i;
        if (row < NNODES) {
            float dv = dinv[row];
            #pragma unroll
            for (int cf = 0; cf < 4; ++cf)
                Y[(long)row * 64 + cf * 16 + cl] = (unsigned short)f2bf(acc[cf][i] * dv);
        }
    }
}

// ---------- CSR gather layer 2: out[v] = dinv[v]*(Hs[v]+sum Hs[s]) + b2 (bf16) ----------
__global__ __launch_bounds__(256) void k_gather2(const int* __restrict__ rp,
                                                 const int* __restrict__ csr_src,
                                                 const float* __restrict__ dinv,
                                                 const unsigned short* __restrict__ Hs,
                                                 const float* __restrict__ bias,
                                                 unsigned short* __restrict__ out) {
    int lane = threadIdx.x & 7;          // 8 lanes/node, 8 ch each
    int grp = threadIdx.x >> 3;
    int v = blockIdx.x * 32 + grp;
    if (v >= NNODES) return;
    int c8 = lane * 8;
    float dd = dinv[v];
    float a[8] = {0, 0, 0, 0, 0, 0, 0, 0};
    const uint4* Hp = (const uint4*)Hs;
    addbf8(Hp[((long)v * 64 + c8) >> 3], a);
    int lo = rp[v], hi = rp[v + 1];
    int i = lo;
    for (; i + 4 <= hi; i += 4) {
        int s0 = csr_src[i], s1 = csr_src[i + 1], s2 = csr_src[i + 2], s3 = csr_src[i + 3];
        uint4 m0 = Hp[((long)s0 * 64 + c8) >> 3];
        uint4 m1 = Hp[((long)s1 * 64 + c8) >> 3];
        uint4 m2 = Hp[((long)s2 * 64 + c8) >> 3];
        uint4 m3 = Hp[((long)s3 * 64 + c8) >> 3];
        addbf8(m0, a); addbf8(m1, a); addbf8(m2, a); addbf8(m3, a);
    }
    for (; i < hi; ++i)
        addbf8(Hp[((long)csr_src[i] * 64 + c8) >> 3], a);
    unsigned t[8];
    #pragma unroll
    for (int j = 0; j < 8; ++j)
        t[j] = (unsigned short)f2bf(fmaf(a[j], dd, bias[c8 + j]));
    uint4 o;
    o.x = t[0] | (t[1] << 16);
    o.y = t[2] | (t[3] << 16);
    o.z = t[4] | (t[5] << 16);
    o.w = t[6] | (t[7] << 16);
    ((uint4*)out)[((long)v * 64 + c8) >> 3] = o;
}

// ---------- pool ----------
__device__ inline int lower_bound_i(const int* a, int n, int key) {
    int lo = 0, hi = n;
    while (lo < hi) {
        int mid = (lo + hi) >> 1;
        if (a[mid] < key) lo = mid + 1; else hi = mid;
    }
    return lo;
}

__global__ __launch_bounds__(256) void k_pool(const unsigned short* __restrict__ h2,
                                              const int* __restrict__ batch,
                                              float* __restrict__ out) {
    int g = blockIdx.x >> 4;
    int slice = blockIdx.x & 15;
    int lo = lower_bound_i(batch, NNODES, g);
    int hi = lower_bound_i(batch, NNODES, g + 1);
    int ch = threadIdx.x & 63;
    int part = threadIdx.x >> 6;
    float acc = 0.f;
    for (int v = lo + slice * 4 + part; v < hi; v += 64)
        acc += bf2f(h2[(long)v * 64 + ch]);
    __shared__ float red[256];
    red[threadIdx.x] = acc;
    __syncthreads();
    if (part == 0) {
        float s = red[ch] + red[64 + ch] + red[128 + ch] + red[192 + ch];
        atomicAdd(&out[g * 64 + ch], s);
    }
}

// ---------- launch ----------
extern "C" void kernel_launch(void* const* d_in, const int* in_sizes, int n_in,
                              void* d_out, int out_size, void* d_ws, size_t ws_size,
                              hipStream_t stream) {
    const float* x   = (const float*)d_in[0];
    const int* ei    = (const int*)d_in[1];
    const int* batch = (const int*)d_in[2];
    const float* W1  = (const float*)d_in[3];
    const float* b1  = (const float*)d_in[4];
    const float* W2  = (const float*)d_in[5];
    const float* b2  = (const float*)d_in[6];
    float* out = (float*)d_out;

    char* ws = (char*)d_ws;
    float* dinv   = (float*)ws;                                 // 200 KB
    int*   rp     = (int*)(ws + (256 << 10));                   // 50001 ints
    int*   bsum   = (int*)(ws + (512 << 10));                   // 196 ints
    int*   cursor = (int*)(ws + (576 << 10));                   // 200 KB
    int*   csr    = (int*)(ws + (1u << 20));                    // 2.4 MB
    unsigned short* Wf1 = (unsigned short*)(ws + (3600u << 10));            // 32 KB
    unsigned short* Wf2 = (unsigned short*)(ws + (3600u << 10) + (32 << 10)); // 16 KB
    unsigned short* bufA = (unsigned short*)(ws + (4u << 20));              // 12.8 MB
    unsigned short* bufB = (unsigned short*)(ws + (4u << 20) + (size_t)NNODES * 128 * 2); // 6.4 MB

    // init (zero rp/out, build W frags)
    k_init0<<<16, 256, 0, stream>>>(W1, W2, Wf1, Wf2, rp, out);

    // mega1: GEMM1 (blocks 0..195, no dinv) || degree count (blocks 196..781)
    k_mega1<<<GEMM_BLKS + (NEDGES / 4 + 255) / 256, 256, 0, stream>>>(x, Wf1, bufA, ei, rp);

    // scan cascade -> rowptr/cursor/dinv ; scatter -> csr
    k_bsum<<<SCAN_BLOCKS, 256, 0, stream>>>(rp, bsum);
    k_scan_bsum<<<1, 256, 0, stream>>>(bsum);
    k_scan_final<<<SCAN_BLOCKS, 256, 0, stream>>>(rp, bsum, cursor, dinv);
    k_scatter<<<(NEDGES / 4 + 255) / 256, 256, 0, stream>>>(ei, cursor, csr);

    // fused gather1(+bias+relu, per-edge dinv[src]) -> @W2 -> Hs2
    k_gather_gemm<<<(NNODES + 63) / 64, 256, 0, stream>>>(rp, csr, dinv, bufA, b1, Wf2, bufB);

    // gather2 (+bias) -> bufA region
    k_gather2<<<(NNODES + 31) / 32, 256, 0, stream>>>(rp, csr, dinv, bufB, b2, bufA);

    // pool
    k_pool<<<NGRAPHS * 16, 256, 0, stream>>>(bufA, batch, out);
}

// Round 9
// 135.311 us; speedup vs baseline: 1.2847x; 1.0257x over previous
//
#include <hip/hip_runtime.h>

#define NNODES 50000
#define NEDGES 600000
#define NGRAPHS 64
#define NREP 8
#define SCAN_BLOCKS ((NNODES + 255) / 256)   // 196

typedef __attribute__((ext_vector_type(8))) short short8;
typedef __attribute__((ext_vector_type(4))) float f32x4;

__device__ inline short f2bf(float f) {
    unsigned u = __float_as_uint(f);
    u = (u + 0x7fffu + ((u >> 16) & 1u)) >> 16;   // RNE
    return (short)u;
}
__device__ inline float bf2f(unsigned short s) {
    return __uint_as_float(((unsigned)s) << 16);
}
__device__ inline float bf_lo(unsigned w) { return __uint_as_float(w << 16); }
__device__ inline float bf_hi(unsigned w) { return __uint_as_float(w & 0xffff0000u); }
__device__ inline void fmabf8(const uint4 m, float n, float* a) {
    a[0] = fmaf(bf_lo(m.x), n, a[0]); a[1] = fmaf(bf_hi(m.x), n, a[1]);
    a[2] = fmaf(bf_lo(m.y), n, a[2]); a[3] = fmaf(bf_hi(m.y), n, a[3]);
    a[4] = fmaf(bf_lo(m.z), n, a[4]); a[5] = fmaf(bf_hi(m.z), n, a[5]);
    a[6] = fmaf(bf_lo(m.w), n, a[6]); a[7] = fmaf(bf_hi(m.w), n, a[7]);
}
__device__ inline void addbf8(const uint4 m, float* a) {
    a[0] += bf_lo(m.x); a[1] += bf_hi(m.x);
    a[2] += bf_lo(m.y); a[3] += bf_hi(m.y);
    a[4] += bf_lo(m.z); a[5] += bf_hi(m.z);
    a[6] += bf_lo(m.w); a[7] += bf_hi(m.w);
}

// ---------- init: W frag tables, zero cnt replicas, rp[0], out ----------
__device__ inline uint4 make_frag(const float* __restrict__ W, int M, int idx) {
    int lane = idx & 63, ks = (idx >> 6) & 3, cf = idx >> 8;
    int c = cf * 16 + (lane & 15);
    int k0 = ks * 32 + (lane >> 4) * 8;
    unsigned t[8];
    #pragma unroll
    for (int j = 0; j < 8; ++j)
        t[j] = (unsigned short)f2bf(W[(k0 + j) * M + c]);
    uint4 o;
    o.x = t[0] | (t[1] << 16);
    o.y = t[2] | (t[3] << 16);
    o.z = t[4] | (t[5] << 16);
    o.w = t[6] | (t[7] << 16);
    return o;
}

__global__ __launch_bounds__(256) void k_init0(const float* __restrict__ W1,
                                               const float* __restrict__ W2,
                                               unsigned short* __restrict__ Wf1,
                                               unsigned short* __restrict__ Wf2,
                                               int* __restrict__ cnt,
                                               int* __restrict__ rp,
                                               float* __restrict__ dout) {
    int idx = blockIdx.x * 256 + threadIdx.x;     // 32 blocks = 8192 threads
    for (int i = idx; i < NREP * NNODES; i += 8192) cnt[i] = 0;
    if (idx == 0) rp[0] = 0;
    if (idx < NGRAPHS * 64) dout[idx] = 0.f;
    if (idx < 2048) {
        ((uint4*)Wf1)[idx] = make_frag(W1, 128, idx);
    } else if (idx < 3072) {
        ((uint4*)Wf2)[idx - 2048] = make_frag(W2, 64, idx - 2048);
    }
}

// ---------- mega1: blocks 0..195 = GEMM1 (Y = bf16(x@W1)); rest = replicated degree count ----------
#define GEMM_BLKS 196
__global__ __launch_bounds__(256) void k_mega1(const float* __restrict__ X,
                                               const unsigned short* __restrict__ Wf,
                                               unsigned short* __restrict__ Y,
                                               const int* __restrict__ ei,
                                               int* __restrict__ cnt) {
    const int tid = threadIdx.x;
    if (blockIdx.x >= GEMM_BLKS) {
        int idx = (blockIdx.x - GEMM_BLKS) * 256 + tid;     // 4 edges/thread
        if (idx * 4 < NEDGES) {
            int4 d = ((const int4*)(ei + NEDGES))[idx];
            int e0 = idx * 4;
            atomicAdd(&cnt[((e0 + 0) & 7) * NNODES + d.x], 1);
            atomicAdd(&cnt[((e0 + 1) & 7) * NNODES + d.y], 1);
            atomicAdd(&cnt[((e0 + 2) & 7) * NNODES + d.z], 1);
            atomicAdd(&cnt[((e0 + 3) & 7) * NNODES + d.w], 1);
        }
        return;
    }
    constexpr int CF = 8;
    constexpr int SLOTS = CF * 4 * 64;   // 2048
    __shared__ uint4 Bl[SLOTS];
    for (int i = tid; i < SLOTS; i += 256) Bl[i] = ((const uint4*)Wf)[i];
    __syncthreads();

    const short8* Bs8 = (const short8*)Bl;
    const int lane = tid & 63;
    const int wave = tid >> 6;
    const int qr = lane >> 4;
    const int cl = lane & 15;
    const int wid = blockIdx.x * 4 + wave;
    const int ngroups = (NNODES + 63) / 64;   // 782
    if (wid >= ngroups) return;

    const int base = wid * 64;
    short8 a[4][4];
    #pragma unroll
    for (int r = 0; r < 4; ++r) {
        int arow = base + r * 16 + cl;
        bool ok = arow < NNODES;
        #pragma unroll
        for (int ks = 0; ks < 4; ++ks) {
            short8 v = (short8)0;
            if (ok) {
                const float* xp = X + (long)arow * 128 + ks * 32 + qr * 8;
                float4 x0 = *reinterpret_cast<const float4*>(xp);
                float4 x1 = *reinterpret_cast<const float4*>(xp + 4);
                v[0] = f2bf(x0.x); v[1] = f2bf(x0.y); v[2] = f2bf(x0.z); v[3] = f2bf(x0.w);
                v[4] = f2bf(x1.x); v[5] = f2bf(x1.y); v[6] = f2bf(x1.z); v[7] = f2bf(x1.w);
            }
            a[r][ks] = v;
        }
    }
    f32x4 acc[4][CF];
    #pragma unroll
    for (int r = 0; r < 4; ++r)
        #pragma unroll
        for (int cf = 0; cf < CF; ++cf)
            acc[r][cf] = (f32x4){0.f, 0.f, 0.f, 0.f};
    #pragma unroll
    for (int cf = 0; cf < CF; ++cf)
        #pragma unroll
        for (int ks = 0; ks < 4; ++ks) {
            short8 b = Bs8[(cf * 4 + ks) * 64 + lane];
            #pragma unroll
            for (int r = 0; r < 4; ++r)
                acc[r][cf] = __builtin_amdgcn_mfma_f32_16x16x32_bf16(a[r][ks], b, acc[r][cf], 0, 0, 0);
        }
    #pragma unroll
    for (int r = 0; r < 4; ++r) {
        int row0 = base + r * 16 + qr * 4;
        #pragma unroll
        for (int i = 0; i < 4; ++i) {
            int row = row0 + i;
            if (row < NNODES) {
                #pragma unroll
                for (int cf = 0; cf < CF; ++cf)
                    Y[(long)row * 128 + cf * 16 + cl] = (unsigned short)f2bf(acc[r][cf][i]);
            }
        }
    }
}

// ---------- scan cascade over summed replicas ----------
__global__ __launch_bounds__(256) void k_bsum(const int* __restrict__ cnt,
                                              int* __restrict__ bsum) {
    __shared__ int red[256];
    int idx = blockIdx.x * 256 + threadIdx.x;
    int c = 0;
    if (idx < NNODES) {
        #pragma unroll
        for (int r = 0; r < NREP; ++r) c += cnt[r * NNODES + idx];
    }
    red[threadIdx.x] = c;
    __syncthreads();
    for (int off = 128; off > 0; off >>= 1) {
        if (threadIdx.x < off) red[threadIdx.x] += red[threadIdx.x + off];
        __syncthreads();
    }
    if (threadIdx.x == 0) bsum[blockIdx.x] = red[0];
}

__global__ __launch_bounds__(256) void k_scan_bsum(int* __restrict__ bsum) {
    __shared__ int s[256];
    int t = threadIdx.x;
    s[t] = (t < SCAN_BLOCKS) ? bsum[t] : 0;
    __syncthreads();
    for (int off = 1; off < 256; off <<= 1) {
        int u = (t >= off) ? s[t - off] : 0;
        __syncthreads();
        s[t] += u;
        __syncthreads();
    }
    if (t < SCAN_BLOCKS) bsum[t] = s[t];
}

// scan -> rowptr(incl), per-replica cursor bases, dinv
__global__ __launch_bounds__(256) void k_scan_final(const int* __restrict__ cnt,
                                                    int* __restrict__ rp,
                                                    const int* __restrict__ bsum,
                                                    int* __restrict__ cur,
                                                    float* __restrict__ dinv) {
    __shared__ int s[256];
    int t = threadIdx.x;
    int idx = blockIdx.x * 256 + t;
    int cr[NREP];
    int c = 0;
    if (idx < NNODES) {
        #pragma unroll
        for (int r = 0; r < NREP; ++r) { cr[r] = cnt[r * NNODES + idx]; c += cr[r]; }
    } else {
        #pragma unroll
        for (int r = 0; r < NREP; ++r) cr[r] = 0;
    }
    s[t] = c;
    __syncthreads();
    for (int off = 1; off < 256; off <<= 1) {
        int u = (t >= off) ? s[t - off] : 0;
        __syncthreads();
        s[t] += u;
        __syncthreads();
    }
    int incl = s[t] + (blockIdx.x ? bsum[blockIdx.x - 1] : 0);
    if (idx < NNODES) {
        rp[1 + idx] = incl;
        int run = incl - c;
        #pragma unroll
        for (int r = 0; r < NREP; ++r) { cur[r * NNODES + idx] = run; run += cr[r]; }
        dinv[idx] = rsqrtf((float)c + 1.0f);
    }
}

__global__ __launch_bounds__(256) void k_scatter(const int* __restrict__ ei,
                                                 int* __restrict__ cur,
                                                 int* __restrict__ csr_src) {
    int idx = blockIdx.x * 256 + threadIdx.x;       // 4 edges/thread
    if (idx * 4 >= NEDGES) return;
    int4 sv = ((const int4*)ei)[idx];
    int4 dv = ((const int4*)(ei + NEDGES))[idx];
    int e0 = idx * 4;
    int p0 = atomicAdd(&cur[((e0 + 0) & 7) * NNODES + dv.x], 1); csr_src[p0] = sv.x;
    int p1 = atomicAdd(&cur[((e0 + 1) & 7) * NNODES + dv.y], 1); csr_src[p1] = sv.y;
    int p2 = atomicAdd(&cur[((e0 + 2) & 7) * NNODES + dv.z], 1); csr_src[p2] = sv.z;
    int p3 = atomicAdd(&cur[((e0 + 3) & 7) * NNODES + dv.w], 1); csr_src[p3] = sv.w;
}

// ---------- fused: gather layer-1 (per-edge dinv[src], relu+bias) -> LDS -> @W2 ----------
__global__ __launch_bounds__(256) void k_gather_gemm(const int* __restrict__ rp,
                                                     const int* __restrict__ csr_src,
                                                     const float* __restrict__ dinv,
                                                     const unsigned short* __restrict__ Hs,
                                                     const float* __restrict__ b1,
                                                     const unsigned short* __restrict__ Wf2,
                                                     unsigned short* __restrict__ Y) {
    __shared__ uint4 Bl[1024];                 // W2 frags, 16 KB
    __shared__ unsigned short h1[64 * 128];    // 16 KB, XOR-swizzled rows
    const int tid = threadIdx.x;
    const int lane = tid & 63;
    const int wave = tid >> 6;
    for (int i = tid; i < 1024; i += 256) Bl[i] = ((const uint4*)Wf2)[i];

    const int grp = lane >> 4;
    const int ln = lane & 15;
    const int c8 = ln * 8;
    const int base = blockIdx.x * 64;
    const uint4* Hp = (const uint4*)Hs;
    float4 bv0 = *reinterpret_cast<const float4*>(b1 + c8);
    float4 bv1 = *reinterpret_cast<const float4*>(b1 + c8 + 4);
    float bb[8] = {bv0.x, bv0.y, bv0.z, bv0.w, bv1.x, bv1.y, bv1.z, bv1.w};

    #pragma unroll
    for (int p = 0; p < 4; ++p) {
        int vloc = wave * 16 + p * 4 + grp;
        int v = base + vloc;
        uint4 o = {0u, 0u, 0u, 0u};
        if (v < NNODES) {
            float a[8] = {0, 0, 0, 0, 0, 0, 0, 0};
            float dd = dinv[v];
            fmabf8(Hp[((long)v * 128 + c8) >> 3], dd, a);   // self * dinv[v]
            int lo = rp[v], hi = rp[v + 1];
            int i = lo;
            for (; i + 4 <= hi; i += 4) {
                int s0 = csr_src[i], s1 = csr_src[i + 1];
                int s2 = csr_src[i + 2], s3 = csr_src[i + 3];
                float n0 = dinv[s0], n1 = dinv[s1], n2 = dinv[s2], n3 = dinv[s3];
                uint4 m0 = Hp[((long)s0 * 128 + c8) >> 3];
                uint4 m1 = Hp[((long)s1 * 128 + c8) >> 3];
                uint4 m2 = Hp[((long)s2 * 128 + c8) >> 3];
                uint4 m3 = Hp[((long)s3 * 128 + c8) >> 3];
                fmabf8(m0, n0, a); fmabf8(m1, n1, a);
                fmabf8(m2, n2, a); fmabf8(m3, n3, a);
            }
            for (; i < hi; ++i) {
                int s = csr_src[i];
                fmabf8(Hp[((long)s * 128 + c8) >> 3], dinv[s], a);
            }
            unsigned t[8];
            #pragma unroll
            for (int j = 0; j < 8; ++j) {
                float y = fmaxf(fmaf(a[j], dd, bb[j]), 0.f);
                t[j] = (unsigned short)f2bf(y);
            }
            o.x = t[0] | (t[1] << 16);
            o.y = t[2] | (t[3] << 16);
            o.z = t[4] | (t[5] << 16);
            o.w = t[6] | (t[7] << 16);
        }
        int byte = (vloc * 256 + c8 * 2) ^ ((vloc & 7) << 4);
        *reinterpret_cast<uint4*>((char*)h1 + byte) = o;
    }
    __syncthreads();

    // Phase B: rows wave*16..+15 ; A-frag: row=wave*16+cl, ch=ks*32+qr*8
    const int qr = lane >> 4;
    const int cl = lane & 15;
    const int arow = wave * 16 + cl;
    short8 afr[4];
    #pragma unroll
    for (int ks = 0; ks < 4; ++ks) {
        int byte = (arow * 256 + (ks * 32 + qr * 8) * 2) ^ ((arow & 7) << 4);
        afr[ks] = *reinterpret_cast<const short8*>((const char*)h1 + byte);
    }
    const short8* Bs8 = (const short8*)Bl;
    f32x4 acc[4];
    #pragma unroll
    for (int cf = 0; cf < 4; ++cf) acc[cf] = (f32x4){0.f, 0.f, 0.f, 0.f};
    #pragma unroll
    for (int cf = 0; cf < 4; ++cf)
        #pragma unroll
        for (int ks = 0; ks < 4; ++ks)
            acc[cf] = __builtin_amdgcn_mfma_f32_16x16x32_bf16(afr[ks], Bs8[(cf * 4 + ks) * 64 + lane], acc[cf], 0, 0, 0);
    #pragma unroll
    for (int i = 0; i < 4; ++i) {
        int row = base + wave * 16 + qr * 4 + i;
        if (row < NNODES) {
            float dv = dinv[row];
            #pragma unroll
            for (int cf = 0; cf < 4; ++cf)
                Y[(long)row * 64 + cf * 16 + cl] = (unsigned short)f2bf(acc[cf][i] * dv);
        }
    }
}

// ---------- CSR gather layer 2: out[v] = dinv[v]*(Hs[v]+sum Hs[s]) + b2 (bf16) ----------
__global__ __launch_bounds__(256) void k_gather2(const int* __restrict__ rp,
                                                 const int* __restrict__ csr_src,
                                                 const float* __restrict__ dinv,
                                                 const unsigned short* __restrict__ Hs,
                                                 const float* __restrict__ bias,
                                                 unsigned short* __restrict__ out) {
    int lane = threadIdx.x & 7;          // 8 lanes/node, 8 ch each
    int grp = threadIdx.x >> 3;
    int v = blockIdx.x * 32 + grp;
    if (v >= NNODES) return;
    int c8 = lane * 8;
    float dd = dinv[v];
    float a[8] = {0, 0, 0, 0, 0, 0, 0, 0};
    const uint4* Hp = (const uint4*)Hs;
    addbf8(Hp[((long)v * 64 + c8) >> 3], a);
    int lo = rp[v], hi = rp[v + 1];
    int i = lo;
    for (; i + 4 <= hi; i += 4) {
        int s0 = csr_src[i], s1 = csr_src[i + 1], s2 = csr_src[i + 2], s3 = csr_src[i + 3];
        uint4 m0 = Hp[((long)s0 * 64 + c8) >> 3];
        uint4 m1 = Hp[((long)s1 * 64 + c8) >> 3];
        uint4 m2 = Hp[((long)s2 * 64 + c8) >> 3];
        uint4 m3 = Hp[((long)s3 * 64 + c8) >> 3];
        addbf8(m0, a); addbf8(m1, a); addbf8(m2, a); addbf8(m3, a);
    }
    for (; i < hi; ++i)
        addbf8(Hp[((long)csr_src[i] * 64 + c8) >> 3], a);
    unsigned t[8];
    #pragma unroll
    for (int j = 0; j < 8; ++j)
        t[j] = (unsigned short)f2bf(fmaf(a[j], dd, bias[c8 + j]));
    uint4 o;
    o.x = t[0] | (t[1] << 16);
    o.y = t[2] | (t[3] << 16);
    o.z = t[4] | (t[5] << 16);
    o.w = t[6] | (t[7] << 16);
    ((uint4*)out)[((long)v * 64 + c8) >> 3] = o;
}

// ---------- pool ----------
__device__ inline int lower_bound_i(const int* a, int n, int key) {
    int lo = 0, hi = n;
    while (lo < hi) {
        int mid = (lo + hi) >> 1;
        if (a[mid] < key) lo = mid + 1; else hi = mid;
    }
    return lo;
}

__global__ __launch_bounds__(256) void k_pool(const unsigned short* __restrict__ h2,
                                              const int* __restrict__ batch,
                                              float* __restrict__ out) {
    int g = blockIdx.x >> 4;
    int slice = blockIdx.x & 15;
    int lo = lower_bound_i(batch, NNODES, g);
    int hi = lower_bound_i(batch, NNODES, g + 1);
    int ch = threadIdx.x & 63;
    int part = threadIdx.x >> 6;
    float acc = 0.f;
    for (int v = lo + slice * 4 + part; v < hi; v += 64)
        acc += bf2f(h2[(long)v * 64 + ch]);
    __shared__ float red[256];
    red[threadIdx.x] = acc;
    __syncthreads();
    if (part == 0) {
        float s = red[ch] + red[64 + ch] + red[128 + ch] + red[192 + ch];
        atomicAdd(&out[g * 64 + ch], s);
    }
}

// ---------- launch ----------
extern "C" void kernel_launch(void* const* d_in, const int* in_sizes, int n_in,
                              void* d_out, int out_size, void* d_ws, size_t ws_size,
                              hipStream_t stream) {
    const float* x   = (const float*)d_in[0];
    const int* ei    = (const int*)d_in[1];
    const int* batch = (const int*)d_in[2];
    const float* W1  = (const float*)d_in[3];
    const float* b1  = (const float*)d_in[4];
    const float* W2  = (const float*)d_in[5];
    const float* b2  = (const float*)d_in[6];
    float* out = (float*)d_out;

    char* ws = (char*)d_ws;
    float* dinv = (float*)ws;                                   // 200 KB
    int*   rp   = (int*)(ws + (256 << 10));                     // 50001 ints
    int*   bsum = (int*)(ws + (512 << 10));                     // 196 ints
    int*   cnt  = (int*)(ws + (1u << 20));                      // 1.6 MB (8 replicas)
    int*   cur  = (int*)(ws + (3u << 20));                      // 1.6 MB (8 replicas)
    int*   csr  = (int*)(ws + (5u << 20));                      // 2.4 MB
    unsigned short* Wf1 = (unsigned short*)(ws + (7680u << 10));              // 32 KB
    unsigned short* Wf2 = (unsigned short*)(ws + (7680u << 10) + (32 << 10)); // 16 KB
    unsigned short* bufA = (unsigned short*)(ws + (8u << 20));                // 12.8 MB
    unsigned short* bufB = (unsigned short*)(ws + (8u << 20) + (size_t)NNODES * 128 * 2); // 6.4 MB

    // init (zero cnt/out, rp[0]=0, build W frags)
    k_init0<<<32, 256, 0, stream>>>(W1, W2, Wf1, Wf2, cnt, rp, out);

    // mega1: GEMM1 (blocks 0..195) || replicated degree count (blocks 196..781)
    k_mega1<<<GEMM_BLKS + (NEDGES / 4 + 255) / 256, 256, 0, stream>>>(x, Wf1, bufA, ei, cnt);

    // scan cascade -> rowptr / per-replica cursors / dinv ; scatter -> csr
    k_bsum<<<SCAN_BLOCKS, 256, 0, stream>>>(cnt, bsum);
    k_scan_bsum<<<1, 256, 0, stream>>>(bsum);
    k_scan_final<<<SCAN_BLOCKS, 256, 0, stream>>>(cnt, rp, bsum, cur, dinv);
    k_scatter<<<(NEDGES / 4 + 255) / 256, 256, 0, stream>>>(ei, cur, csr);

    // fused gather1(+bias+relu, per-edge dinv[src]) -> @W2 -> Hs2
    k_gather_gemm<<<(NNODES + 63) / 64, 256, 0, stream>>>(rp, csr, dinv, bufA, b1, Wf2, bufB);

    // gather2 (+bias) -> bufA region
    k_gather2<<<(NNODES + 31) / 32, 256, 0, stream>>>(rp, csr, dinv, bufB, b2, bufA);

    // pool
    k_pool<<<NGRAPHS * 16, 256, 0, stream>>>(bufA, batch, out);
}